// Round 9
// baseline (339.146 us; speedup 1.0000x reference)
//
#include <hip/hip_runtime.h>
#include <math.h>

typedef unsigned short ushort_t;
typedef __attribute__((ext_vector_type(8))) short short8x;
typedef __attribute__((ext_vector_type(4))) float f32x4;

#define SUBS 8
#define CAP 128  // per (32-node bucket, sub): mean ~64, CAP=128 ~ +8 sigma

__device__ __forceinline__ unsigned f2bf(float f) {
  unsigned u = __float_as_uint(f);
  u += 0x7fff + ((u >> 16) & 1);
  return u >> 16;
}
__device__ __forceinline__ float bf2f(ushort_t u) {
  return __uint_as_float(((unsigned)u) << 16);
}
// sum over the 8-lane half of each 16-lane DPP row (pure VALU, no LDS pipe)
__device__ __forceinline__ float dpp_red8(float v) {
  v += __int_as_float(__builtin_amdgcn_update_dpp(0, __float_as_int(v), 0xB1, 0xF, 0xF, true));   // quad_perm xor1
  v += __int_as_float(__builtin_amdgcn_update_dpp(0, __float_as_int(v), 0x4E, 0xF, 0xF, true));   // quad_perm xor2
  v += __int_as_float(__builtin_amdgcn_update_dpp(0, __float_as_int(v), 0x141, 0xF, 0xF, true));  // row_half_mirror
  return v;
}

struct GArgs {
  const float* Wl[2];
  const float* bl[2];
  const float* Wr[2];
  const float* br[2];
  const float* Wres[2];
  const float* bias[2];
};

// identity column layout, col in [0,640): dir=col/320; cc<128: Wl, <256: Wr, else Wres
__device__ __forceinline__ float wval1(const GArgs& ga, int col, int k) {
  int dir = col >= 320 ? 1 : 0;
  int cc = col - dir * 320;
  return cc < 128 ? ga.Wl[dir][k * 128 + cc]
       : cc < 256 ? ga.Wr[dir][k * 128 + (cc - 128)]
                  : ga.Wres[dir][k * 64 + (cc - 256)];
}
__device__ __forceinline__ float bval(const GArgs& ga, int col) {
  int dir = col >= 320 ? 1 : 0;
  int cc = col - dir * 320;
  return cc < 128 ? ga.bl[dir][cc]
       : cc < 256 ? ga.br[dir][cc - 128]
                  : ga.bias[dir][cc - 256];
}

// ------------------------- weight packing ----------------------------------
// WT1[640][128] (full K), WT2[640][128] (block-diag: k<64 -> dir0, k>=64 -> dir1)

__global__ __launch_bounds__(128) void pack_kernel(GArgs g1, GArgs g2,
                                                   ushort_t* __restrict__ WT1,
                                                   ushort_t* __restrict__ WT2,
                                                   float* __restrict__ bc1,
                                                   float* __restrict__ bc2) {
  int b = blockIdx.x;
  int k = threadIdx.x;
  if (b < 640) {
    WT1[b * 128 + k] = (ushort_t)f2bf(wval1(g1, b, k));
  } else if (b < 1280) {
    int c = b - 640;
    int dir = c >= 320 ? 1 : 0;
    int cc = c - dir * 320;
    float v = 0.f;
    if ((k >> 6) == dir) {
      int k2 = k & 63;
      v = cc < 128 ? g2.Wl[dir][k2 * 128 + cc]
        : cc < 256 ? g2.Wr[dir][k2 * 128 + (cc - 128)]
                   : g2.Wres[dir][k2 * 64 + (cc - 256)];
    }
    WT2[c * 128 + k] = (ushort_t)f2bf(v);
  } else {
    for (int c = k; c < 640; c += 128) {
      bc1[c] = bval(g1, c);
      bc2[c] = bval(g2, c);
    }
  }
}

// ------------------------- bf16 MFMA GEMM body -----------------------------
// Y[N][640] = A[N][128] * WT^T + bc.  Block: 64 rows x 128 cols, 4 waves.
// AF32=1: A is f32 (inline cvt to bf16 while staging).

template <int AF32>
__device__ __forceinline__ void gemm_body(const float* Af, const ushort_t* Ab,
                                          const ushort_t* WT, const float* bc,
                                          ushort_t* Y, int N, int rb, int cb,
                                          ushort_t* lds) {
  const int tid = threadIdx.x;
  const int lane = tid & 63;
  const int w = tid >> 6;
  const int m0 = rb * 64;
  const int cbase = cb * 128 + w * 32;

  // stage A tile (64 x 128 bf16), xor-swizzled source, linear LDS write
#pragma unroll
  for (int c = 0; c < 4; ++c) {
    int Lb = (tid + c * 256) * 16;
    int row = Lb >> 8, within = Lb & 255;
    int so = within ^ ((row & 7) << 4);
    int grow = m0 + row;
    if (grow >= N) grow = N - 1;
    if (AF32) {
      const float* src = Af + (size_t)grow * 128 + (so >> 1);
      float4 a = *(const float4*)src;
      float4 b = *(const float4*)(src + 4);
      uint4 o;
      o.x = f2bf(a.x) | (f2bf(a.y) << 16);
      o.y = f2bf(a.z) | (f2bf(a.w) << 16);
      o.z = f2bf(b.x) | (f2bf(b.y) << 16);
      o.w = f2bf(b.z) | (f2bf(b.w) << 16);
      ((uint4*)lds)[tid + c * 256] = o;
    } else {
      ((uint4*)lds)[tid + c * 256] = *(const uint4*)(Ab + (size_t)grow * 128 + (so >> 1));
    }
  }

  // B fragments (vectorized, L2-hot)
  short8x bf[4][2];
#pragma unroll
  for (int ks = 0; ks < 4; ++ks)
#pragma unroll
    for (int ns = 0; ns < 2; ++ns) {
      int col = cbase + ns * 16 + (lane & 15);
      bf[ks][ns] = *(const short8x*)(WT + (size_t)col * 128 + ks * 32 + (lane >> 4) * 8);
    }

  __syncthreads();

  f32x4 z = {0.f, 0.f, 0.f, 0.f};
  f32x4 acc[4][2];
#pragma unroll
  for (int ms = 0; ms < 4; ++ms) {
    acc[ms][0] = z;
    acc[ms][1] = z;
  }
#pragma unroll
  for (int ks = 0; ks < 4; ++ks) {
    short8x af[4];
#pragma unroll
    for (int ms = 0; ms < 4; ++ms) {
      int row = ms * 16 + (lane & 15);
      int byte = row * 256 + ((ks * 64 + (lane >> 4) * 16) ^ ((row & 7) << 4));
      af[ms] = *(const short8x*)((const char*)lds + byte);
    }
#pragma unroll
    for (int ms = 0; ms < 4; ++ms) {
      acc[ms][0] = __builtin_amdgcn_mfma_f32_16x16x32_bf16(af[ms], bf[ks][0], acc[ms][0], 0, 0, 0);
      acc[ms][1] = __builtin_amdgcn_mfma_f32_16x16x32_bf16(af[ms], bf[ks][1], acc[ms][1], 0, 0, 0);
    }
  }

#pragma unroll
  for (int ms = 0; ms < 4; ++ms)
#pragma unroll
    for (int ns = 0; ns < 2; ++ns) {
      int col = cbase + ns * 16 + (lane & 15);
      float bv = bc[col];
#pragma unroll
      for (int r = 0; r < 4; ++r) {
        int grow = m0 + ms * 16 + (lane >> 4) * 4 + r;
        if (grow < N) Y[(size_t)grow * 640 + col] = (ushort_t)f2bf(acc[ms][ns][r] + bv);
      }
    }
}

// ---------------- fused front-end: bin | gemm1 | copy_x --------------------
// bin: 4 edges/thread; all 8 atomicAdds issued back-to-back (distinct VGPRs)
// before the 8 dependent scatter stores -> 4x more chains in flight.

__global__ __launch_bounds__(256) void k_front(
    const float* __restrict__ x, const int* __restrict__ ei, int E, int N,
    int* __restrict__ st0, int* __restrict__ st1, int* __restrict__ cnt0,
    int* __restrict__ cnt1, const ushort_t* __restrict__ WT1,
    const float* __restrict__ bc1, ushort_t* __restrict__ Y,
    float* __restrict__ out, int nbin, int ngemm, int nrow) {
  __shared__ ushort_t lds[8192];
  const int bid = blockIdx.x;
  const int t = threadIdx.x;
  if (bid < nbin) {
    const int sub = bid & (SUBS - 1);
    const int i0 = (bid * 256 + t) * 4;
    if (i0 >= E) return;
    if (i0 + 3 < E && (E & 3) == 0) {
      int4 sv = *(const int4*)(ei + i0);
      int4 dv = *(const int4*)(ei + E + i0);
      int ss[4] = {sv.x, sv.y, sv.z, sv.w};
      int dd[4] = {dv.x, dv.y, dv.z, dv.w};
      int pos[8], tgt[8];
#pragma unroll
      for (int j = 0; j < 4; ++j) {
        int c0 = (dd[j] >> 5) * SUBS + sub;
        tgt[j] = c0 * CAP;
        pos[j] = atomicAdd(&cnt0[c0], 1);
      }
#pragma unroll
      for (int j = 0; j < 4; ++j) {
        int c1 = (ss[j] >> 5) * SUBS + sub;
        tgt[4 + j] = c1 * CAP;
        pos[4 + j] = atomicAdd(&cnt1[c1], 1);
      }
#pragma unroll
      for (int j = 0; j < 4; ++j)
        if (pos[j] < CAP) st0[tgt[j] + pos[j]] = (ss[j] << 5) | (dd[j] & 31);
#pragma unroll
      for (int j = 0; j < 4; ++j)
        if (pos[4 + j] < CAP) st1[tgt[4 + j] + pos[4 + j]] = (dd[j] << 5) | (ss[j] & 31);
    } else {
      for (int i = i0; i < min(i0 + 4, E); ++i) {
        int s = ei[i], d = ei[E + i];
        int c0 = (d >> 5) * SUBS + sub;
        int i_ = atomicAdd(&cnt0[c0], 1);
        if (i_ < CAP) st0[c0 * CAP + i_] = (s << 5) | (d & 31);
        int c1 = (s >> 5) * SUBS + sub;
        int j_ = atomicAdd(&cnt1[c1], 1);
        if (j_ < CAP) st1[c1 * CAP + j_] = (d << 5) | (s & 31);
      }
    }
  } else if (bid < nbin + ngemm) {
    int gb = bid - nbin;
    gemm_body<1>(x, nullptr, WT1, bc1, Y, N, gb % nrow, gb / nrow, lds);
  } else {
    int i = (bid - nbin - ngemm) * 256 + t;
    if (i < N * 32) {
      float4 v = ((const float4*)x)[i];
      ((float4*)out)[(size_t)(i >> 5) * 64 + 32 + (i & 31)] = v;
    }
  }
}

// ---------------------------- layer-2 GEMM ---------------------------------

__global__ __launch_bounds__(256) void gemm2_kernel(const ushort_t* __restrict__ A,
                                                    const ushort_t* __restrict__ WT,
                                                    const float* __restrict__ bc,
                                                    ushort_t* __restrict__ Y, int N) {
  __shared__ ushort_t lds[8192];
  gemm_body<0>(nullptr, A, WT, bc, Y, N, blockIdx.x, blockIdx.y, lds);
}

// -------- fused aggregation: one block per 32-node bucket ------------------
// Head-split lanes: 16 lanes/edge; lane jj owns 8 channels of head (jj>>3).
// Logit reduce = 3-stage DPP; weight = exp2(p) with log2(e) folded into att.
// lnbr FULLY zero-initialized -> all gather-address loads unconditional and
// safe (out-of-range slots read offset 0 = row 0 of Y; value masked by wgt=0).
// No max subtraction (logits tiny; softmax ratio identical).

template <int MODE>  // 0: L1 (LayerNorm, bf16 out [N][128]), 1: L2 (f32 out [N][256])
__global__ __launch_bounds__(256) void agg_bucket(
    const ushort_t* __restrict__ Y, const int* __restrict__ st0,
    const int* __restrict__ st1, const int* __restrict__ cnt0,
    const int* __restrict__ cnt1, const float* __restrict__ attA,
    const float* __restrict__ attB, const float* __restrict__ lng0,
    const float* __restrict__ lnb0, const float* __restrict__ lng1,
    const float* __restrict__ lnb1, void* __restrict__ outp, int N) {
  __shared__ int lnbr[SUBS * CAP + 8];  // pre-multiplied row byte offsets + pad
  __shared__ int hist[32], offs[32], cur[32];
  __shared__ int csub[SUBS + 1];
  const int b = blockIdx.x;
  const int dir = blockIdx.y;
  const int t = threadIdx.x;
  const int* st = dir ? st1 : st0;
  const int* cnt = dir ? cnt1 : cnt0;
  const float* att = dir ? attB : attA;

  // full zero-init of lnbr: unwritten slots must read as valid offset 0
  for (int i = t; i < SUBS * CAP + 8; i += 256) lnbr[i] = 0;
  if (t < 32) {
    hist[t] = 0;
    cur[t] = 0;
  }
  if (t == 64) {
    int a = 0;
    for (int s = 0; s < SUBS; ++s) {
      csub[s] = a;
      a += min(cnt[b * SUBS + s], CAP);
    }
    csub[SUBS] = a;
  }
  __syncthreads();
#pragma unroll
  for (int s = 0; s < SUBS; ++s) {
    int base = csub[s], c = csub[s + 1] - base;
    for (int i = t; i < c; i += 256)
      atomicAdd(&hist[st[(b * SUBS + s) * CAP + i] & 31], 1);
  }
  __syncthreads();
  if (t < 32) {
    int v = hist[t], inc = v;
#pragma unroll
    for (int o = 1; o < 32; o <<= 1) {
      int u = __shfl_up(inc, o);
      if (t >= o) inc += u;
    }
    offs[t] = inc - v;
  }
  __syncthreads();
#pragma unroll
  for (int s = 0; s < SUBS; ++s) {
    int base = csub[s], c = csub[s + 1] - base;
    for (int i = t; i < c; i += 256) {
      int e = st[(b * SUBS + s) * CAP + i];
      int r = e & 31;
      lnbr[offs[r] + atomicAdd(&cur[r], 1)] = (int)((unsigned)e >> 5) * 1280;
    }
  }
  __syncthreads();

  const int wv = t >> 6, lane = t & 63, g = lane >> 4, jj = lane & 15;
  const float L2E = 1.4426950408889634f;
  float av[8];
  {
    float4 a0 = *(const float4*)(att + jj * 8);
    float4 a1 = *(const float4*)(att + jj * 8 + 4);
    av[0] = a0.x * L2E; av[1] = a0.y * L2E; av[2] = a0.z * L2E; av[3] = a0.w * L2E;
    av[4] = a1.x * L2E; av[5] = a1.y * L2E; av[6] = a1.z * L2E; av[7] = a1.w * L2E;
  }
  const char* Yb = (const char*)Y + dir * 640 + jj * 16;  // + row byte offset -> xl chans

  for (int r = wv; r < 32; r += 4) {
    const int n = b * 32 + r;
    if (n >= N) break;
    const char* rowp = (const char*)Y + (size_t)n * 1280 + dir * 640;

    float xi[8];
    {
      short8x v = *(const short8x*)(rowp + 256 + jj * 16);  // xr block
#pragma unroll
      for (int q = 0; q < 8; ++q) xi[q] = bf2f((ushort_t)v[q]);
    }
    float d = 0.f;
    float acc[8];
#pragma unroll
    for (int q = 0; q < 8; ++q) acc[q] = 0.f;

    const int beg = offs[r], deg = hist[r];
    if (deg > 0) {
      int off = lnbr[beg + g];
      short8x vj = *(const short8x*)(Yb + (size_t)(unsigned)off);
      for (int k0 = 0; k0 < deg; k0 += 4) {
        int offn = lnbr[beg + k0 + 4 + g];  // zero-filled tail -> safe
        short8x vn = *(const short8x*)(Yb + (size_t)(unsigned)offn);
        float xj[8];
#pragma unroll
        for (int q = 0; q < 8; ++q) xj[q] = bf2f((ushort_t)vj[q]);
        float p = 0.f;
#pragma unroll
        for (int q = 0; q < 8; ++q) {
          float e = xi[q] + xj[q];
          e = fmaxf(e, 0.2f * e);  // leaky-relu(0.2), slope > 0
          p = fmaf(e, av[q], p);
        }
        p = dpp_red8(p);  // per-head logit*log2e (lanes 0-7: h0, 8-15: h1)
        float wgt = (k0 + g < deg) ? __builtin_amdgcn_exp2f(p) : 0.f;
        d += wgt;
#pragma unroll
        for (int q = 0; q < 8; ++q) acc[q] = fmaf(xj[q], wgt, acc[q]);
        vj = vn;
      }
#pragma unroll
      for (int o = 16; o <= 32; o <<= 1) {  // combine the 4 edge-groups
        d += __shfl_xor(d, o);
#pragma unroll
        for (int q = 0; q < 8; ++q) acc[q] += __shfl_xor(acc[q], o);
      }
    }
    float inv = deg > 0 ? 1.f / d : 0.f;
    float v[8];
#pragma unroll
    for (int q = 0; q < 8; ++q) {
      float tq = acc[q] * inv;
      v[q] = 0.5f * (tq + __shfl_xor(tq, 8));  // mean over heads
    }
    {
      short8x rv = *(const short8x*)(rowp + 512 + (jj & 7) * 16);  // res block
#pragma unroll
      for (int q = 0; q < 8; ++q) v[q] += bf2f((ushort_t)rv[q]);
    }

    if (MODE == 0) {
      float s = 0.f;
#pragma unroll
      for (int q = 0; q < 8; ++q) s += v[q];
      s += __shfl_xor(s, 1);
      s += __shfl_xor(s, 2);
      s += __shfl_xor(s, 4);
      float mu = s * (1.f / 64.f);
      float vs = 0.f;
#pragma unroll
      for (int q = 0; q < 8; ++q) {
        float dv = v[q] - mu;
        vs += dv * dv;
      }
      vs += __shfl_xor(vs, 1);
      vs += __shfl_xor(vs, 2);
      vs += __shfl_xor(vs, 4);
      float rstd = rsqrtf(vs * (1.f / 64.f) + 1e-5f);
      if (g == 0 && jj < 8) {
        const float* lg = dir ? lng1 : lng0;
        const float* lb = dir ? lnb1 : lnb0;
        unsigned o2[8];
#pragma unroll
        for (int q = 0; q < 8; ++q) {
          int c = jj * 8 + q;
          float y = (v[q] - mu) * rstd * lg[c] + lb[c];
          y = fmaxf(y, 0.01f * y);
          o2[q] = f2bf(y);
        }
        uint4 pk;
        pk.x = o2[0] | (o2[1] << 16);
        pk.y = o2[2] | (o2[3] << 16);
        pk.z = o2[4] | (o2[5] << 16);
        pk.w = o2[6] | (o2[7] << 16);
        *(uint4*)((ushort_t*)outp + (size_t)n * 128 + dir * 64 + jj * 8) = pk;
      }
    } else {
      if (g == 0 && jj < 8) {
        float* op = (float*)outp + (size_t)n * 256 + dir * 64 + jj * 8;
        float4 o0, o1;
        o0.x = fmaxf(v[0], 0.01f * v[0]);
        o0.y = fmaxf(v[1], 0.01f * v[1]);
        o0.z = fmaxf(v[2], 0.01f * v[2]);
        o0.w = fmaxf(v[3], 0.01f * v[3]);
        o1.x = fmaxf(v[4], 0.01f * v[4]);
        o1.y = fmaxf(v[5], 0.01f * v[5]);
        o1.z = fmaxf(v[6], 0.01f * v[6]);
        o1.w = fmaxf(v[7], 0.01f * v[7]);
        *(float4*)op = o0;
        *(float4*)(op + 4) = o1;
      }
    }
  }
}

// ---------------------------------------------------------------------------

extern "C" void kernel_launch(void* const* d_in, const int* in_sizes, int n_in,
                              void* d_out, int out_size, void* d_ws, size_t ws_size,
                              hipStream_t stream) {
  const float* x = (const float*)d_in[0];
  const int* ei = (const int*)d_in[1];
  const int N = in_sizes[0] / 128;
  const int E = in_sizes[1] / 2;
  float* out = (float*)d_out;
  const int nbuck = (N + 31) >> 5;

  char* p = (char*)d_ws;
  auto carve = [&](size_t bytes) {
    char* q = p;
    p += ((bytes + 255) & ~(size_t)255);
    return q;
  };
  int* cnt = (int*)carve((size_t)2 * nbuck * SUBS * 4);
  int* st0 = (int*)carve((size_t)nbuck * SUBS * CAP * 4);
  int* st1 = (int*)carve((size_t)nbuck * SUBS * CAP * 4);
  ushort_t* Y1 = (ushort_t*)carve((size_t)N * 640 * 2);
  ushort_t* A2 = (ushort_t*)carve((size_t)N * 128 * 2);
  ushort_t* WT1 = (ushort_t*)carve(640 * 128 * 2);
  ushort_t* WT2 = (ushort_t*)carve(640 * 128 * 2);
  float* bc1 = (float*)carve(640 * 4);
  float* bc2 = (float*)carve(640 * 4);
  int* cnt0 = cnt;
  int* cnt1 = cnt + (size_t)nbuck * SUBS;

  auto F = [&](int i) { return (const float*)d_in[i]; };
  GArgs g1, g2;
  // layer 1: dir0 = c1d (2..8), dir1 = c1t (9..15)
  g1.Wl[0] = F(2);  g1.bl[0] = F(3);  g1.Wr[0] = F(4);  g1.br[0] = F(5);
  g1.Wres[0] = F(7); g1.bias[0] = F(8);
  g1.Wl[1] = F(9);  g1.bl[1] = F(10); g1.Wr[1] = F(11); g1.br[1] = F(12);
  g1.Wres[1] = F(14); g1.bias[1] = F(15);
  // layer 2: dir0 = c2d (16..22), dir1 = c2t (23..29)
  g2.Wl[0] = F(16); g2.bl[0] = F(17); g2.Wr[0] = F(18); g2.br[0] = F(19);
  g2.Wres[0] = F(21); g2.bias[0] = F(22);
  g2.Wl[1] = F(23); g2.bl[1] = F(24); g2.Wr[1] = F(25); g2.br[1] = F(26);
  g2.Wres[1] = F(28); g2.bias[1] = F(29);

  hipMemsetAsync(cnt, 0, (size_t)2 * nbuck * SUBS * 4, stream);

  pack_kernel<<<1281, 128, 0, stream>>>(g1, g2, WT1, WT2, bc1, bc2);

  const int nbin = (E + 1023) / 1024;
  const int nrow = (N + 63) / 64;
  const int ngemm = nrow * 5;
  const int ncopy = (N * 32 + 255) / 256;
  k_front<<<nbin + ngemm + ncopy, 256, 0, stream>>>(
      x, ei, E, N, st0, st1, cnt0, cnt1, WT1, bc1, Y1, out, nbin, ngemm, nrow);

  const dim3 ga(nbuck, 2);
  agg_bucket<0><<<ga, 256, 0, stream>>>(Y1, st0, st1, cnt0, cnt1, F(6), F(13),
                                        F(30), F(31), F(32), F(33), A2, N);
  gemm2_kernel<<<dim3(nrow, 5), 256, 0, stream>>>(A2, WT2, bc2, Y1, N);
  agg_bucket<1><<<ga, 256, 0, stream>>>(Y1, st0, st1, cnt0, cnt1, F(20), F(27),
                                        nullptr, nullptr, nullptr, nullptr, out, N);
}

// Round 10
// 305.841 us; speedup vs baseline: 1.1089x; 1.1089x over previous
//
#include <hip/hip_runtime.h>
#include <math.h>

typedef unsigned short ushort_t;
typedef __attribute__((ext_vector_type(8))) short short8x;
typedef __attribute__((ext_vector_type(4))) float f32x4;

#define CSHIFT 9        // coarse bucket = 512 nodes
#define CC 12288        // entries per coarse bucket (mean ~8163, +45 sigma)
#define EPB 4096        // edges per pass-A block
#define ECAP 1024       // staged entries per fine bucket (mean ~512)
#define NCMAX 128       // max coarse buckets (N<65536 -> <=128)

__device__ __forceinline__ unsigned f2bf(float f) {
  unsigned u = __float_as_uint(f);
  u += 0x7fff + ((u >> 16) & 1);
  return u >> 16;
}
__device__ __forceinline__ float bf2f(ushort_t u) {
  return __uint_as_float(((unsigned)u) << 16);
}
// sum over the 8-lane half of each 16-lane DPP row (pure VALU, no LDS pipe)
__device__ __forceinline__ float dpp_red8(float v) {
  v += __int_as_float(__builtin_amdgcn_update_dpp(0, __float_as_int(v), 0xB1, 0xF, 0xF, true));   // quad_perm xor1
  v += __int_as_float(__builtin_amdgcn_update_dpp(0, __float_as_int(v), 0x4E, 0xF, 0xF, true));   // quad_perm xor2
  v += __int_as_float(__builtin_amdgcn_update_dpp(0, __float_as_int(v), 0x141, 0xF, 0xF, true));  // row_half_mirror
  return v;
}

struct GArgs {
  const float* Wl[2];
  const float* bl[2];
  const float* Wr[2];
  const float* br[2];
  const float* Wres[2];
  const float* bias[2];
};

// identity column layout, col in [0,640): dir=col/320; cc<128: Wl, <256: Wr, else Wres
__device__ __forceinline__ float wval1(const GArgs& ga, int col, int k) {
  int dir = col >= 320 ? 1 : 0;
  int cc = col - dir * 320;
  return cc < 128 ? ga.Wl[dir][k * 128 + cc]
       : cc < 256 ? ga.Wr[dir][k * 128 + (cc - 128)]
                  : ga.Wres[dir][k * 64 + (cc - 256)];
}
__device__ __forceinline__ float bval(const GArgs& ga, int col) {
  int dir = col >= 320 ? 1 : 0;
  int cc = col - dir * 320;
  return cc < 128 ? ga.bl[dir][cc]
       : cc < 256 ? ga.br[dir][cc - 128]
                  : ga.bias[dir][cc - 256];
}

// ------------------------- weight packing ----------------------------------
// WT1[640][128] (full K), WT2[640][128] (block-diag: k<64 -> dir0, k>=64 -> dir1)

__global__ __launch_bounds__(128) void pack_kernel(GArgs g1, GArgs g2,
                                                   ushort_t* __restrict__ WT1,
                                                   ushort_t* __restrict__ WT2,
                                                   float* __restrict__ bc1,
                                                   float* __restrict__ bc2) {
  int b = blockIdx.x;
  int k = threadIdx.x;
  if (b < 640) {
    WT1[b * 128 + k] = (ushort_t)f2bf(wval1(g1, b, k));
  } else if (b < 1280) {
    int c = b - 640;
    int dir = c >= 320 ? 1 : 0;
    int cc = c - dir * 320;
    float v = 0.f;
    if ((k >> 6) == dir) {
      int k2 = k & 63;
      v = cc < 128 ? g2.Wl[dir][k2 * 128 + cc]
        : cc < 256 ? g2.Wr[dir][k2 * 128 + (cc - 128)]
                   : g2.Wres[dir][k2 * 64 + (cc - 256)];
    }
    WT2[c * 128 + k] = (ushort_t)f2bf(v);
  } else {
    for (int c = k; c < 640; c += 128) {
      bc1[c] = bval(g1, c);
      bc2[c] = bval(g2, c);
    }
  }
}

// ------------------------- bf16 MFMA GEMM body -----------------------------
// Y[N][640] = A[N][128] * WT^T + bc.  Block: 64 rows x 128 cols, 4 waves.
// AF32=1: A is f32 (inline cvt to bf16 while staging).

template <int AF32>
__device__ __forceinline__ void gemm_body(const float* Af, const ushort_t* Ab,
                                          const ushort_t* WT, const float* bc,
                                          ushort_t* Y, int N, int rb, int cb,
                                          ushort_t* lds) {
  const int tid = threadIdx.x;
  const int lane = tid & 63;
  const int w = tid >> 6;
  const int m0 = rb * 64;
  const int cbase = cb * 128 + w * 32;

  // stage A tile (64 x 128 bf16), xor-swizzled source, linear LDS write
#pragma unroll
  for (int c = 0; c < 4; ++c) {
    int Lb = (tid + c * 256) * 16;
    int row = Lb >> 8, within = Lb & 255;
    int so = within ^ ((row & 7) << 4);
    int grow = m0 + row;
    if (grow >= N) grow = N - 1;
    if (AF32) {
      const float* src = Af + (size_t)grow * 128 + (so >> 1);
      float4 a = *(const float4*)src;
      float4 b = *(const float4*)(src + 4);
      uint4 o;
      o.x = f2bf(a.x) | (f2bf(a.y) << 16);
      o.y = f2bf(a.z) | (f2bf(a.w) << 16);
      o.z = f2bf(b.x) | (f2bf(b.y) << 16);
      o.w = f2bf(b.z) | (f2bf(b.w) << 16);
      ((uint4*)lds)[tid + c * 256] = o;
    } else {
      ((uint4*)lds)[tid + c * 256] = *(const uint4*)(Ab + (size_t)grow * 128 + (so >> 1));
    }
  }

  // B fragments (vectorized, L2-hot)
  short8x bf[4][2];
#pragma unroll
  for (int ks = 0; ks < 4; ++ks)
#pragma unroll
    for (int ns = 0; ns < 2; ++ns) {
      int col = cbase + ns * 16 + (lane & 15);
      bf[ks][ns] = *(const short8x*)(WT + (size_t)col * 128 + ks * 32 + (lane >> 4) * 8);
    }

  __syncthreads();

  f32x4 z = {0.f, 0.f, 0.f, 0.f};
  f32x4 acc[4][2];
#pragma unroll
  for (int ms = 0; ms < 4; ++ms) {
    acc[ms][0] = z;
    acc[ms][1] = z;
  }
#pragma unroll
  for (int ks = 0; ks < 4; ++ks) {
    short8x af[4];
#pragma unroll
    for (int ms = 0; ms < 4; ++ms) {
      int row = ms * 16 + (lane & 15);
      int byte = row * 256 + ((ks * 64 + (lane >> 4) * 16) ^ ((row & 7) << 4));
      af[ms] = *(const short8x*)((const char*)lds + byte);
    }
#pragma unroll
    for (int ms = 0; ms < 4; ++ms) {
      acc[ms][0] = __builtin_amdgcn_mfma_f32_16x16x32_bf16(af[ms], bf[ks][0], acc[ms][0], 0, 0, 0);
      acc[ms][1] = __builtin_amdgcn_mfma_f32_16x16x32_bf16(af[ms], bf[ks][1], acc[ms][1], 0, 0, 0);
    }
  }

#pragma unroll
  for (int ms = 0; ms < 4; ++ms)
#pragma unroll
    for (int ns = 0; ns < 2; ++ns) {
      int col = cbase + ns * 16 + (lane & 15);
      float bv = bc[col];
#pragma unroll
      for (int r = 0; r < 4; ++r) {
        int grow = m0 + ms * 16 + (lane >> 4) * 4 + r;
        if (grow < N) Y[(size_t)grow * 640 + col] = (ushort_t)f2bf(acc[ms][ns][r] + bv);
      }
    }
}

// ---------------- fused front-end: coarse-bin | gemm1 | copy_x -------------
// Pass A: radix partition into 512-node coarse buckets. Per block: LDS hist
// (98 counters), ONE global atomicAdd per (block,bucket), then scatter with
// ~42-entry contiguous runs per bucket. Entry = (nbr<<16)|node (both <2^16).

__global__ __launch_bounds__(256) void k_front(
    const float* __restrict__ x, const int* __restrict__ ei, int E, int N,
    int* __restrict__ gc0, int* __restrict__ gc1, int* __restrict__ ctail0,
    int* __restrict__ ctail1, const ushort_t* __restrict__ WT1,
    const float* __restrict__ bc1, ushort_t* __restrict__ Y,
    float* __restrict__ out, int nbinA, int ngemm, int nrow) {
  __shared__ ushort_t lds[8192];
  const int bid = blockIdx.x;
  const int t = threadIdx.x;
  if (bid < nbinA) {
    int* h0 = (int*)lds;        // [NCMAX]
    int* h1 = h0 + NCMAX;
    int* b0 = h1 + NCMAX;
    int* b1 = b0 + NCMAX;
    const int e0 = bid * EPB;
    const int e1 = min(e0 + EPB, E);
    for (int i = t; i < NCMAX; i += 256) {
      h0[i] = 0;
      h1[i] = 0;
    }
    __syncthreads();
    for (int i = e0 + t; i < e1; i += 256) {
      int s = ei[i], d = ei[E + i];
      atomicAdd(&h0[d >> CSHIFT], 1);
      atomicAdd(&h1[s >> CSHIFT], 1);
    }
    __syncthreads();
    for (int c = t; c < NCMAX; c += 256) {
      int n0 = h0[c], n1 = h1[c];
      b0[c] = n0 ? atomicAdd(&ctail0[c], n0) : 0;
      b1[c] = n1 ? atomicAdd(&ctail1[c], n1) : 0;
      h0[c] = 0;
      h1[c] = 0;
    }
    __syncthreads();
    for (int i = e0 + t; i < e1; i += 256) {
      int s = ei[i], d = ei[E + i];
      int c0 = d >> CSHIFT;
      int p0 = b0[c0] + atomicAdd(&h0[c0], 1);
      if (p0 < CC) gc0[c0 * CC + p0] = (s << 16) | d;
      int c1 = s >> CSHIFT;
      int p1 = b1[c1] + atomicAdd(&h1[c1], 1);
      if (p1 < CC) gc1[c1 * CC + p1] = (d << 16) | s;
    }
  } else if (bid < nbinA + ngemm) {
    int gb = bid - nbinA;
    gemm_body<1>(x, nullptr, WT1, bc1, Y, N, gb % nrow, gb / nrow, lds);
  } else {
    int i = (bid - nbinA - ngemm) * 256 + t;
    if (i < N * 32) {
      float4 v = ((const float4*)x)[i];
      ((float4*)out)[(size_t)(i >> 5) * 64 + 32 + (i & 31)] = v;
    }
  }
}

// ---------------------------- layer-2 GEMM ---------------------------------

__global__ __launch_bounds__(256) void gemm2_kernel(const ushort_t* __restrict__ A,
                                                    const ushort_t* __restrict__ WT,
                                                    const float* __restrict__ bc,
                                                    ushort_t* __restrict__ Y, int N) {
  __shared__ ushort_t lds[8192];
  gemm_body<0>(nullptr, A, WT, bc, Y, N, blockIdx.x, blockIdx.y, lds);
}

// -------- fused aggregation: one block per 32-node fine bucket -------------
// Prologue: stream the parent coarse bucket's entries (coalesced, L2-hot;
// 16 blocks share each), filter (node>>5)==fb into LDS, build local CSR.
// Head-split lanes: 16 lanes/edge; lane jj owns 8 channels of head (jj>>3).
// Logit reduce = 3-stage DPP; weight = exp2(p) with log2(e) folded into att.
// lnbr FULLY zero-initialized -> unconditional prefetch reads are safe.
// No max subtraction (logits tiny; softmax ratio identical).

template <int MODE>  // 0: L1 (LayerNorm, bf16 out [N][128]), 1: L2 (f32 out [N][256])
__global__ __launch_bounds__(256) void agg_bucket(
    const ushort_t* __restrict__ Y, const int* __restrict__ gc0,
    const int* __restrict__ gc1, const int* __restrict__ ctail0,
    const int* __restrict__ ctail1, const float* __restrict__ attA,
    const float* __restrict__ attB, const float* __restrict__ lng0,
    const float* __restrict__ lnb0, const float* __restrict__ lng1,
    const float* __restrict__ lnb1, void* __restrict__ outp, int N) {
  __shared__ int ebuf[ECAP];
  __shared__ int lnbr[ECAP + 8];  // pre-multiplied row byte offsets + pad
  __shared__ int hist[32], offs[32], cur[32];
  __shared__ int ecnt;
  const int fb = blockIdx.x;       // fine bucket (32 nodes)
  const int cb = fb >> 4;          // parent coarse bucket (512 nodes)
  const int dir = blockIdx.y;
  const int t = threadIdx.x;
  const int* gc = dir ? gc1 : gc0;
  const int* ctail = dir ? ctail1 : ctail0;
  const float* att = dir ? attB : attA;

  for (int i = t; i < ECAP + 8; i += 256) lnbr[i] = 0;
  if (t < 32) {
    hist[t] = 0;
    cur[t] = 0;
  }
  if (t == 64) ecnt = 0;
  __syncthreads();

  // filter coarse bucket -> staged fine entries
  {
    const int cntc = min(ctail[cb], CC);
    const int* src = gc + cb * CC;
    for (int i = t; i < cntc; i += 256) {
      int e = src[i];
      if (((e & 0xFFFF) >> 5) == fb) {
        int idx = atomicAdd(&ecnt, 1);
        if (idx < ECAP) ebuf[idx] = e;
      }
    }
  }
  __syncthreads();
  const int tot = min(ecnt, ECAP);
  for (int i = t; i < tot; i += 256) atomicAdd(&hist[ebuf[i] & 31], 1);
  __syncthreads();
  if (t < 32) {
    int v = hist[t], inc = v;
#pragma unroll
    for (int o = 1; o < 32; o <<= 1) {
      int u = __shfl_up(inc, o);
      if (t >= o) inc += u;
    }
    offs[t] = inc - v;
  }
  __syncthreads();
  for (int i = t; i < tot; i += 256) {
    int e = ebuf[i];
    int r = e & 31;
    lnbr[offs[r] + atomicAdd(&cur[r], 1)] = (int)((unsigned)e >> 16) * 1280;
  }
  __syncthreads();

  const int wv = t >> 6, lane = t & 63, g = lane >> 4, jj = lane & 15;
  const float L2E = 1.4426950408889634f;
  float av[8];
  {
    float4 a0 = *(const float4*)(att + jj * 8);
    float4 a1 = *(const float4*)(att + jj * 8 + 4);
    av[0] = a0.x * L2E; av[1] = a0.y * L2E; av[2] = a0.z * L2E; av[3] = a0.w * L2E;
    av[4] = a1.x * L2E; av[5] = a1.y * L2E; av[6] = a1.z * L2E; av[7] = a1.w * L2E;
  }
  const char* Yb = (const char*)Y + dir * 640 + jj * 16;  // + row byte offset -> xl chans

  for (int r = wv; r < 32; r += 4) {
    const int n = fb * 32 + r;
    if (n >= N) break;
    const char* rowp = (const char*)Y + (size_t)n * 1280 + dir * 640;

    float xi[8];
    {
      short8x v = *(const short8x*)(rowp + 256 + jj * 16);  // xr block
#pragma unroll
      for (int q = 0; q < 8; ++q) xi[q] = bf2f((ushort_t)v[q]);
    }
    float d = 0.f;
    float acc[8];
#pragma unroll
    for (int q = 0; q < 8; ++q) acc[q] = 0.f;

    const int beg = offs[r], deg = hist[r];
    if (deg > 0) {
      int off = lnbr[beg + g];
      short8x vj = *(const short8x*)(Yb + (size_t)(unsigned)off);
      for (int k0 = 0; k0 < deg; k0 += 4) {
        int offn = lnbr[beg + k0 + 4 + g];  // zero-filled tail -> safe
        short8x vn = *(const short8x*)(Yb + (size_t)(unsigned)offn);
        float xj[8];
#pragma unroll
        for (int q = 0; q < 8; ++q) xj[q] = bf2f((ushort_t)vj[q]);
        float p = 0.f;
#pragma unroll
        for (int q = 0; q < 8; ++q) {
          float e = xi[q] + xj[q];
          e = fmaxf(e, 0.2f * e);  // leaky-relu(0.2), slope > 0
          p = fmaf(e, av[q], p);
        }
        p = dpp_red8(p);  // per-head logit*log2e (lanes 0-7: h0, 8-15: h1)
        float wgt = (k0 + g < deg) ? __builtin_amdgcn_exp2f(p) : 0.f;
        d += wgt;
#pragma unroll
        for (int q = 0; q < 8; ++q) acc[q] = fmaf(xj[q], wgt, acc[q]);
        vj = vn;
      }
#pragma unroll
      for (int o = 16; o <= 32; o <<= 1) {  // combine the 4 edge-groups
        d += __shfl_xor(d, o);
#pragma unroll
        for (int q = 0; q < 8; ++q) acc[q] += __shfl_xor(acc[q], o);
      }
    }
    float inv = deg > 0 ? 1.f / d : 0.f;
    float v[8];
#pragma unroll
    for (int q = 0; q < 8; ++q) {
      float tq = acc[q] * inv;
      v[q] = 0.5f * (tq + __shfl_xor(tq, 8));  // mean over heads
    }
    {
      short8x rv = *(const short8x*)(rowp + 512 + (jj & 7) * 16);  // res block
#pragma unroll
      for (int q = 0; q < 8; ++q) v[q] += bf2f((ushort_t)rv[q]);
    }

    if (MODE == 0) {
      float s = 0.f;
#pragma unroll
      for (int q = 0; q < 8; ++q) s += v[q];
      s += __shfl_xor(s, 1);
      s += __shfl_xor(s, 2);
      s += __shfl_xor(s, 4);
      float mu = s * (1.f / 64.f);
      float vs = 0.f;
#pragma unroll
      for (int q = 0; q < 8; ++q) {
        float dv = v[q] - mu;
        vs += dv * dv;
      }
      vs += __shfl_xor(vs, 1);
      vs += __shfl_xor(vs, 2);
      vs += __shfl_xor(vs, 4);
      float rstd = rsqrtf(vs * (1.f / 64.f) + 1e-5f);
      if (g == 0 && jj < 8) {
        const float* lg = dir ? lng1 : lng0;
        const float* lb = dir ? lnb1 : lnb0;
        unsigned o2[8];
#pragma unroll
        for (int q = 0; q < 8; ++q) {
          int c = jj * 8 + q;
          float y = (v[q] - mu) * rstd * lg[c] + lb[c];
          y = fmaxf(y, 0.01f * y);
          o2[q] = f2bf(y);
        }
        uint4 pk;
        pk.x = o2[0] | (o2[1] << 16);
        pk.y = o2[2] | (o2[3] << 16);
        pk.z = o2[4] | (o2[5] << 16);
        pk.w = o2[6] | (o2[7] << 16);
        *(uint4*)((ushort_t*)outp + (size_t)n * 128 + dir * 64 + jj * 8) = pk;
      }
    } else {
      if (g == 0 && jj < 8) {
        float* op = (float*)outp + (size_t)n * 256 + dir * 64 + jj * 8;
        float4 o0, o1;
        o0.x = fmaxf(v[0], 0.01f * v[0]);
        o0.y = fmaxf(v[1], 0.01f * v[1]);
        o0.z = fmaxf(v[2], 0.01f * v[2]);
        o0.w = fmaxf(v[3], 0.01f * v[3]);
        o1.x = fmaxf(v[4], 0.01f * v[4]);
        o1.y = fmaxf(v[5], 0.01f * v[5]);
        o1.z = fmaxf(v[6], 0.01f * v[6]);
        o1.w = fmaxf(v[7], 0.01f * v[7]);
        *(float4*)op = o0;
        *(float4*)(op + 4) = o1;
      }
    }
  }
}

// ---------------------------------------------------------------------------

extern "C" void kernel_launch(void* const* d_in, const int* in_sizes, int n_in,
                              void* d_out, int out_size, void* d_ws, size_t ws_size,
                              hipStream_t stream) {
  const float* x = (const float*)d_in[0];
  const int* ei = (const int*)d_in[1];
  const int N = in_sizes[0] / 128;
  const int E = in_sizes[1] / 2;
  float* out = (float*)d_out;
  const int nbuck = (N + 31) >> 5;                 // fine buckets
  const int ncoarse = (N + (1 << CSHIFT) - 1) >> CSHIFT;

  char* p = (char*)d_ws;
  auto carve = [&](size_t bytes) {
    char* q = p;
    p += ((bytes + 255) & ~(size_t)255);
    return q;
  };
  int* ctail = (int*)carve(2 * NCMAX * 4);
  int* gc0 = (int*)carve((size_t)ncoarse * CC * 4);
  int* gc1 = (int*)carve((size_t)ncoarse * CC * 4);
  ushort_t* Y1 = (ushort_t*)carve((size_t)N * 640 * 2);
  ushort_t* A2 = (ushort_t*)carve((size_t)N * 128 * 2);
  ushort_t* WT1 = (ushort_t*)carve(640 * 128 * 2);
  ushort_t* WT2 = (ushort_t*)carve(640 * 128 * 2);
  float* bc1 = (float*)carve(640 * 4);
  float* bc2 = (float*)carve(640 * 4);
  int* ctail0 = ctail;
  int* ctail1 = ctail + NCMAX;

  auto F = [&](int i) { return (const float*)d_in[i]; };
  GArgs g1, g2;
  // layer 1: dir0 = c1d (2..8), dir1 = c1t (9..15)
  g1.Wl[0] = F(2);  g1.bl[0] = F(3);  g1.Wr[0] = F(4);  g1.br[0] = F(5);
  g1.Wres[0] = F(7); g1.bias[0] = F(8);
  g1.Wl[1] = F(9);  g1.bl[1] = F(10); g1.Wr[1] = F(11); g1.br[1] = F(12);
  g1.Wres[1] = F(14); g1.bias[1] = F(15);
  // layer 2: dir0 = c2d (16..22), dir1 = c2t (23..29)
  g2.Wl[0] = F(16); g2.bl[0] = F(17); g2.Wr[0] = F(18); g2.br[0] = F(19);
  g2.Wres[0] = F(21); g2.bias[0] = F(22);
  g2.Wl[1] = F(23); g2.bl[1] = F(24); g2.Wr[1] = F(25); g2.br[1] = F(26);
  g2.Wres[1] = F(28); g2.bias[1] = F(29);

  hipMemsetAsync(ctail, 0, 2 * NCMAX * 4, stream);

  pack_kernel<<<1281, 128, 0, stream>>>(g1, g2, WT1, WT2, bc1, bc2);

  const int nbinA = (E + EPB - 1) / EPB;
  const int nrow = (N + 63) / 64;
  const int ngemm = nrow * 5;
  const int ncopy = (N * 32 + 255) / 256;
  k_front<<<nbinA + ngemm + ncopy, 256, 0, stream>>>(
      x, ei, E, N, gc0, gc1, ctail0, ctail1, WT1, bc1, Y1, out,
      nbinA, ngemm, nrow);

  const dim3 ga(nbuck, 2);
  agg_bucket<0><<<ga, 256, 0, stream>>>(Y1, gc0, gc1, ctail0, ctail1, F(6), F(13),
                                        F(30), F(31), F(32), F(33), A2, N);
  gemm2_kernel<<<dim3(nrow, 5), 256, 0, stream>>>(A2, WT2, bc2, Y1, N);
  agg_bucket<1><<<ga, 256, 0, stream>>>(Y1, gc0, gc1, ctail0, ctail1, F(20), F(27),
                                        nullptr, nullptr, nullptr, nullptr, out, N);
}